// Round 1
// baseline (17.138 us; speedup 1.0000x reference)
//
#include <hip/hip_runtime.h>
#include <math.h>

// out[idx] = prod_{b=0}^{23} A[b][(idx>>b)&1]
//   A[b][0] = |cos(y[23-b]/2)| , A[b][1] = |sin(y[23-b]/2)|
// (wire i is the MSB-first bit: bit position b corresponds to wire 23-b;
//  RY(-y): cos(-t)=cos t, |sin(-t)|=|sin t|, and abs(prod)=prod(abs).)
//
// Write-bound kernel: 2^24 floats = 64 MiB out. Factor the product so each
// float4 store costs ~6 VALU ops:
//   bits 13..23 <- blockIdx (2048 blocks)  : block-uniform prefix P
//   bits 10..12 <- unrolled iter (8 iters) : I
//   bits  2..9  <- threadIdx (256 thr)     : per-thread T
//   bits  0..1  <- float4 lanes            : q0..q3

constexpr int NW = 24;

__global__ __launch_bounds__(256) void qstate_kernel(const float* __restrict__ y,
                                                     float4* __restrict__ out4) {
    __shared__ float A0[NW];
    __shared__ float A1[NW];
    const int tid = threadIdx.x;
    if (tid < NW) {
        float h = 0.5f * y[NW - 1 - tid];
        A0[tid] = fabsf(cosf(h));
        A1[tid] = fabsf(sinf(h));
    }
    __syncthreads();

    const unsigned blk = blockIdx.x;  // 2^11 blocks -> idx bits 13..23

    // Block-uniform prefix over idx bits 13..23.
    float P = 1.0f;
#pragma unroll
    for (int b = 13; b < 24; ++b)
        P *= ((blk >> (b - 13)) & 1) ? A1[b] : A0[b];

    // Thread-fixed product over idx bits 2..9.
    float T = 1.0f;
#pragma unroll
    for (int b = 2; b < 10; ++b)
        T *= ((tid >> (b - 2)) & 1) ? A1[b] : A0[b];

    const float PT = P * T;

    // Low-2-bit combos (idx bits 1,0).
    const float q0 = A0[1] * A0[0];
    const float q1 = A0[1] * A1[0];
    const float q2 = A1[1] * A0[0];
    const float q3 = A1[1] * A1[0];

    const unsigned vbase = (blk << 11) | (unsigned)tid;  // float4 index base

#pragma unroll
    for (int iter = 0; iter < 8; ++iter) {
        // idx bits 10..12 from iter (compile-time after unroll).
        float I = ((iter & 1) ? A1[10] : A0[10]) *
                  ((iter & 2) ? A1[11] : A0[11]) *
                  ((iter & 4) ? A1[12] : A0[12]);
        float p = PT * I;
        float4 r = make_float4(p * q0, p * q1, p * q2, p * q3);
        out4[vbase + (unsigned)iter * 256u] = r;
    }
}

extern "C" void kernel_launch(void* const* d_in, const int* in_sizes, int n_in,
                              void* d_out, int out_size, void* d_ws, size_t ws_size,
                              hipStream_t stream) {
    (void)in_sizes; (void)n_in; (void)d_ws; (void)ws_size; (void)out_size;
    const float* y = (const float*)d_in[1];  // d_in[0] = x is discarded by the reference
    qstate_kernel<<<2048, 256, 0, stream>>>(y, (float4*)d_out);
}

// Round 3
// 16.553 us; speedup vs baseline: 1.0354x; 1.0354x over previous
//
#include <hip/hip_runtime.h>
#include <math.h>

// out[idx] = prod_{b=0}^{23} A[b][(idx>>b)&1]
//   A[b][0] = |cos(y[23-b]/2)| , A[b][1] = |sin(y[23-b]/2)|
// (wire i maps to bit 23-i; RY(-y): cos unchanged, |sin| unchanged; abs of a
//  product of reals = product of abs.)
//
// Pure write-stream: 2^24 fp32 = 64 MiB out, 96 B in. Floor at the measured
// fill-kernel ceiling (6.3-6.5 TB/s) is ~10.5 us.
//
// Index factorization (float index bits):
//   bits 13..23 <- blockIdx (2048 blocks)  : block-uniform prefix P
//   bits 10..12 <- unrolled iter (8 iters) : I (compile-time selects)
//   bits  2..9  <- threadIdx (256 thr)     : per-thread T
//   bits  0..1  <- float4 lanes            : q0..q3
//
// nt stores via native clang vector type (__builtin_nontemporal_store rejects
// HIP_vector_type structs but accepts ext_vector_type).

constexpr int NW = 24;

typedef float f32x4 __attribute__((ext_vector_type(4)));

__global__ __launch_bounds__(256) void qstate_kernel(const float* __restrict__ y,
                                                     f32x4* __restrict__ out4) {
    __shared__ float A0[NW];
    __shared__ float A1[NW];
    const int tid = threadIdx.x;
    if (tid < NW) {
        float h = 0.5f * y[NW - 1 - tid];
        A0[tid] = fabsf(cosf(h));
        A1[tid] = fabsf(sinf(h));
    }
    __syncthreads();

    const unsigned blk = blockIdx.x;  // 2^11 blocks -> float-index bits 13..23

    // Block-uniform prefix over bits 13..23.
    float P = 1.0f;
#pragma unroll
    for (int b = 13; b < 24; ++b)
        P *= ((blk >> (b - 13)) & 1) ? A1[b] : A0[b];

    // Thread-fixed product over bits 2..9.
    float T = 1.0f;
#pragma unroll
    for (int b = 2; b < 10; ++b)
        T *= ((tid >> (b - 2)) & 1) ? A1[b] : A0[b];

    const float PT = P * T;

    // Hoist loop-needed LDS values into registers.
    const float a10_0 = A0[10], a10_1 = A1[10];
    const float a11_0 = A0[11], a11_1 = A1[11];
    const float a12_0 = A0[12], a12_1 = A1[12];

    // Low-2-bit combos (bits 1,0).
    const float q0 = A0[1] * A0[0];
    const float q1 = A0[1] * A1[0];
    const float q2 = A1[1] * A0[0];
    const float q3 = A1[1] * A1[0];

    const unsigned vbase = (blk << 11) | (unsigned)tid;  // float4 index

#pragma unroll
    for (int iter = 0; iter < 8; ++iter) {
        float I = ((iter & 1) ? a10_1 : a10_0) *
                  ((iter & 2) ? a11_1 : a11_0) *
                  ((iter & 4) ? a12_1 : a12_0);
        float p = PT * I;
        f32x4 r = {p * q0, p * q1, p * q2, p * q3};
        __builtin_nontemporal_store(r, &out4[vbase + (unsigned)iter * 256u]);
    }
}

extern "C" void kernel_launch(void* const* d_in, const int* in_sizes, int n_in,
                              void* d_out, int out_size, void* d_ws, size_t ws_size,
                              hipStream_t stream) {
    (void)in_sizes; (void)n_in; (void)d_ws; (void)ws_size; (void)out_size;
    const float* y = (const float*)d_in[1];  // d_in[0] = x is discarded by the reference
    qstate_kernel<<<2048, 256, 0, stream>>>(y, (f32x4*)d_out);
}